// Round 1
// baseline (4099.126 us; speedup 1.0000x reference)
//
#include <hip/hip_runtime.h>
#include <hip/hip_bf16.h>

// B=64, P=196, T=30, E=D=A=ENC=512, V=30000
#define BB 64
#define PP 196
#define TT 30
#define DD 512
#define VV 30000
#define VPAD 30080           // 235*128
#define MROWS 1856           // 29*64
#define MPAD 1920            // 15*128
#define NBLK 64              // persistent kernel grid
#define ASTR 3072            // A_step row: [x_hi(1024) h_hi(512) x_lo(1024) h_lo(512)]

typedef __attribute__((ext_vector_type(8))) short short8;
typedef __attribute__((ext_vector_type(4))) float f32x4;

__device__ __forceinline__ unsigned short f2bf(float f) {
    unsigned int u = __float_as_uint(f);
    unsigned int r = u + 0x7FFFu + ((u >> 16) & 1u);
    return (unsigned short)(r >> 16);
}
__device__ __forceinline__ float bf2f(unsigned short u) {
    return __uint_as_float(((unsigned int)u) << 16);
}
__device__ __forceinline__ float sigf(float x) { return 1.f / (1.f + __expf(-x)); }
__device__ __forceinline__ float tanh_fast(float x) { return 1.f - 2.f / (1.f + __expf(2.f * x)); }

// ---------------- cast fp32 -> bf16 ----------------
__global__ __launch_bounds__(256) void k_cast(const float* __restrict__ in,
                                              unsigned short* __restrict__ out, int n) {
    int i = blockIdx.x * 256 + threadIdx.x;
    int stride = gridDim.x * 256;
    for (; i < n; i += stride) out[i] = f2bf(in[i]);
}

// ------- transpose fp32 [R][C] -> bf16 out[outr][ostride] at +ooff, zero-fill C..Cpad -------
__global__ __launch_bounds__(256) void k_transpose_cast(const float* __restrict__ in,
                                                        unsigned short* __restrict__ out,
                                                        int R, int C, int Cpad, int ostride, int ooff) {
    __shared__ float tile[32][33];
    int tx = threadIdx.x & 31, ty = threadIdx.x >> 5;  // 32 x 8
    int c0 = blockIdx.x * 32, r0 = blockIdx.y * 32;
#pragma unroll
    for (int i = 0; i < 4; ++i) {
        int r = r0 + ty + i * 8, c = c0 + tx;
        tile[ty + i * 8][tx] = (c < C) ? in[(size_t)r * C + c] : 0.f;
    }
    __syncthreads();
#pragma unroll
    for (int i = 0; i < 4; ++i) {
        int outr = c0 + ty + i * 8, outc = r0 + tx;
        if (outr < Cpad) out[(size_t)outr * ostride + ooff + outc] = f2bf(tile[tx][ty + i * 8]);
    }
}

// ------- transpose fp32 [R][C] -> split bf16 (hi at ooff, lo at looff), exact tiles -------
__global__ __launch_bounds__(256) void k_transpose_cast_split(const float* __restrict__ in,
                                                              unsigned short* __restrict__ out,
                                                              int R, int C, int ostride,
                                                              int ooff, int looff) {
    __shared__ float tile[32][33];
    int tx = threadIdx.x & 31, ty = threadIdx.x >> 5;  // 32 x 8
    int c0 = blockIdx.x * 32, r0 = blockIdx.y * 32;
#pragma unroll
    for (int i = 0; i < 4; ++i) {
        int r = r0 + ty + i * 8, c = c0 + tx;
        tile[ty + i * 8][tx] = in[(size_t)r * C + c];
    }
    __syncthreads();
#pragma unroll
    for (int i = 0; i < 4; ++i) {
        int outr = c0 + ty + i * 8, outc = r0 + tx;
        float v = tile[tx][ty + i * 8];
        unsigned short hi = f2bf(v);
        unsigned short lo = f2bf(v - bf2f(hi));
        out[(size_t)outr * ostride + ooff + outc] = hi;
        out[(size_t)outr * ostride + looff + outc] = lo;
    }
}

// ---------------- zero out[:, 0, :] ----------------
__global__ __launch_bounds__(256) void k_zero0(float* __restrict__ out) {
    int i = blockIdx.x * 256 + threadIdx.x;  // 64*30000
    int b = i / VV, v = i - b * VV;
    out[(size_t)b * (TT * VV) + v] = 0.f;
}

// ---------------- init h0 (split bf16 into A_step), c0 (fp32), zero barrier ----------------
__global__ __launch_bounds__(256) void k_init(const float* __restrict__ pooled,
                                              const float* __restrict__ Wh, const float* __restrict__ bh,
                                              const float* __restrict__ Wc, const float* __restrict__ bc,
                                              unsigned short* __restrict__ A_step,
                                              float* __restrict__ cbuf, int* __restrict__ bar) {
    int b = blockIdx.x >> 1, which = blockIdx.x & 1, t = threadIdx.x;
    if (blockIdx.x == 0 && t < 64) bar[t] = 0;
    const float* W = which ? Wc : Wh;
    const float* bias = which ? bc : bh;
    const float* pr = pooled + b * DD;
    float a0 = 0.f, a1 = 0.f;
#pragma unroll 4
    for (int k = 0; k < DD; ++k) {
        float pv = pr[k];
        a0 += pv * W[k * DD + t];
        a1 += pv * W[k * DD + t + 256];
    }
    float v0 = tanh_fast(a0 + bias[t]);
    float v1 = tanh_fast(a1 + bias[t + 256]);
    if (which == 0) {
        unsigned short hi0 = f2bf(v0), lo0 = f2bf(v0 - bf2f(hi0));
        unsigned short hi1 = f2bf(v1), lo1 = f2bf(v1 - bf2f(hi1));
        A_step[b * ASTR + 1024 + t] = hi0;
        A_step[b * ASTR + 2560 + t] = lo0;
        A_step[b * ASTR + 1024 + t + 256] = hi1;
        A_step[b * ASTR + 2560 + t + 256] = lo1;
    } else {
        cbuf[b * DD + t] = v0;
        cbuf[b * DD + t + 256] = v1;
    }
}

// -------- device-scope grid barrier (all NBLK blocks resident: grid<=CUs, 1 block/CU) --------
__device__ __forceinline__ void gbar(int* bar) {
    __syncthreads();
    if (threadIdx.x == 0) {
        int* cnt = bar;
        int* gen = bar + 32;
        int g = __hip_atomic_load(gen, __ATOMIC_RELAXED, __HIP_MEMORY_SCOPE_AGENT);
        int a = __hip_atomic_fetch_add(cnt, 1, __ATOMIC_ACQ_REL, __HIP_MEMORY_SCOPE_AGENT);
        if (a == NBLK - 1) {
            __hip_atomic_store(cnt, 0, __ATOMIC_RELAXED, __HIP_MEMORY_SCOPE_AGENT);
            __hip_atomic_store(gen, g + 1, __ATOMIC_RELEASE, __HIP_MEMORY_SCOPE_AGENT);
        } else {
            while (__hip_atomic_load(gen, __ATOMIC_ACQUIRE, __HIP_MEMORY_SCOPE_AGENT) == g)
                __builtin_amdgcn_s_sleep(2);
        }
    }
    __syncthreads();
}

// ---------------- persistent recurrence kernel: 29 steps, 3 grid syncs/step ----------------
// Recurrent GEMMs use double-bf16 (hi/lo) 3-product MFMA: a*b ~= ah*bh + al*bh + ah*bl
__global__ __launch_bounds__(256, 1) void k_recur(
    const unsigned short* __restrict__ ep,    // [64*196][512] bf16 enc_proj
    const unsigned short* __restrict__ fb,    // [64*196][512] bf16 feats
    const unsigned short* __restrict__ WdbT,  // [1024][1024]  rows: [Wd|Wbeta] cols, [hi(512)|lo(512)]
    const unsigned short* __restrict__ WT,    // [2048][3072]  rows j: [Wih;Whh]^T, [hi(1536)|lo(1536)]
    const float* __restrict__ bd,
    const float* __restrict__ bbeta,
    const float* __restrict__ wfv,
    const int* __restrict__ caps,
    const float* __restrict__ emb,
    const float* __restrict__ b_ih,
    const float* __restrict__ b_hh,
    unsigned short* __restrict__ A_step,      // [64][3072] bf16: x_hi|h_hi|x_lo|h_lo
    float* __restrict__ cbuf,                 // [64][512] fp32
    float* __restrict__ decp,                 // [64][512] fp32
    float* __restrict__ betap,                // [64][512] fp32
    unsigned short* __restrict__ hb,          // [29*64][512] bf16
    int* __restrict__ bar) {

    const int blk = blockIdx.x, t = threadIdx.x;
    const int lane = t & 63, wave = t >> 6;
    const int r16 = lane & 15, kg = lane >> 4;
    const int swz = kg ^ ((r16 >> 1) & 3);

    __shared__ unsigned short Ash[64 * 32];
    __shared__ unsigned short Asl[64 * 32];
    __shared__ unsigned short Bsh[64 * 32];
    __shared__ unsigned short Bsl[64 * 32];
    __shared__ float dec_s[DD];
    __shared__ float wf_s[DD];
    __shared__ float sc_s[256];
    __shared__ float red_s[256];

    const short8* Ash8 = (const short8*)Ash;
    const short8* Asl8 = (const short8*)Asl;
    const short8* Bsh8 = (const short8*)Bsh;
    const short8* Bsl8 = (const short8*)Bsl;
    const int srow = t >> 2, scs = t & 3;
    const int scsrc = scs ^ ((srow >> 1) & 3);

    for (int ts = 1; ts < TT; ++ts) {
        // ===== Phase A (blocks 0..31): [dec|beta] = h @ [Wd|Wb]  (M=64,N=32/blk,K=512) =====
        if (blk < 32) {
            const int n0 = blk * 32;
            f32x4 acc[2];
#pragma unroll
            for (int j = 0; j < 2; ++j) acc[j] = {0.f, 0.f, 0.f, 0.f};
            for (int k0 = 0; k0 < 512; k0 += 32) {
                ((uint4*)Ash)[t] = *(const uint4*)(A_step + srow * ASTR + 1024 + k0 + scsrc * 8);
                ((uint4*)Asl)[t] = *(const uint4*)(A_step + srow * ASTR + 2560 + k0 + scsrc * 8);
                if (t < 128) {
                    ((uint4*)Bsh)[t] = *(const uint4*)(WdbT + (size_t)(n0 + srow) * 1024 + k0 + scsrc * 8);
                    ((uint4*)Bsl)[t] = *(const uint4*)(WdbT + (size_t)(n0 + srow) * 1024 + 512 + k0 + scsrc * 8);
                }
                __syncthreads();
                short8 ah = Ash8[(wave * 16 + r16) * 4 + swz];
                short8 al = Asl8[(wave * 16 + r16) * 4 + swz];
#pragma unroll
                for (int j = 0; j < 2; ++j) {
                    short8 bh = Bsh8[(j * 16 + r16) * 4 + swz];
                    short8 bl = Bsl8[(j * 16 + r16) * 4 + swz];
                    acc[j] = __builtin_amdgcn_mfma_f32_16x16x32_bf16(ah, bh, acc[j], 0, 0, 0);
                    acc[j] = __builtin_amdgcn_mfma_f32_16x16x32_bf16(al, bh, acc[j], 0, 0, 0);
                    acc[j] = __builtin_amdgcn_mfma_f32_16x16x32_bf16(ah, bl, acc[j], 0, 0, 0);
                }
                __syncthreads();
            }
#pragma unroll
            for (int j = 0; j < 2; ++j) {
                int col = n0 + j * 16 + r16;
#pragma unroll
                for (int r = 0; r < 4; ++r) {
                    int b = wave * 16 + kg * 4 + r;
                    float v = acc[j][r];
                    if (col < 512) decp[b * 512 + col] = v + bd[col];
                    else betap[b * 512 + (col - 512)] = sigf(v + bbeta[col - 512]);
                }
            }
        }
        gbar(bar);

        // ===== Phase B (all 64 blocks, one per b): attention + x assembly =====
        {
            const int b = blk;
            dec_s[t] = decp[b * 512 + t];
            dec_s[t + 256] = decp[b * 512 + t + 256];
            wf_s[t] = wfv[t];
            wf_s[t + 256] = wfv[t + 256];
            __syncthreads();
            const unsigned short* epb = ep + (size_t)(b * PP) * 512;
            for (int p = wave; p < PP; p += 4) {
                uint4 pk = *(const uint4*)(epb + p * 512 + lane * 8);
                const unsigned short* pu = (const unsigned short*)&pk;
                float s = 0.f;
#pragma unroll
                for (int j = 0; j < 8; ++j) {
                    int a = lane * 8 + j;
                    float v = bf2f(pu[j]) + dec_s[a];
                    s += tanh_fast(v) * wf_s[a];
                }
#pragma unroll
                for (int off = 32; off; off >>= 1) s += __shfl_xor(s, off);
                if (lane == 0) sc_s[p] = s;
            }
            __syncthreads();
            float sv = (t < PP) ? sc_s[t] : -1e30f;
            red_s[t] = sv;
            __syncthreads();
            for (int off = 128; off; off >>= 1) {
                if (t < off) red_s[t] = fmaxf(red_s[t], red_s[t + off]);
                __syncthreads();
            }
            float mx = red_s[0];
            __syncthreads();
            float e = (t < PP) ? __expf(sv - mx) : 0.f;
            red_s[t] = e;
            __syncthreads();
            for (int off = 128; off; off >>= 1) {
                if (t < off) red_s[t] += red_s[t + off];
                __syncthreads();
            }
            float denom = red_s[0];
            __syncthreads();
            if (t < PP) sc_s[t] = e / denom;
            __syncthreads();
            const unsigned short* fbb = fb + (size_t)(b * PP) * 512;
            float c0 = 0.f, c1 = 0.f;
#pragma unroll 4
            for (int p = 0; p < PP; ++p) {
                float a = sc_s[p];
                c0 += a * bf2f(fbb[p * 512 + t]);
                c1 += a * bf2f(fbb[p * 512 + t + 256]);
            }
            float g0 = betap[b * 512 + t], g1 = betap[b * 512 + t + 256];
            int tok = caps[b * TT + (ts - 1)];
            const float* er = emb + (size_t)tok * 512;
            unsigned short* xr = A_step + b * ASTR;
            {
                float v;
                unsigned short hi;
                v = er[t];             hi = f2bf(v); xr[t] = hi;           xr[1536 + t] = f2bf(v - bf2f(hi));
                v = er[t + 256];       hi = f2bf(v); xr[t + 256] = hi;     xr[1792 + t] = f2bf(v - bf2f(hi));
                v = g0 * c0;           hi = f2bf(v); xr[512 + t] = hi;     xr[2048 + t] = f2bf(v - bf2f(hi));
                v = g1 * c1;           hi = f2bf(v); xr[768 + t] = hi;     xr[2304 + t] = f2bf(v - bf2f(hi));
            }
        }
        gbar(bar);

        // ===== Phase C (blocks 0..31): gates GEMM (M=64,N=16x4gates,K=1536 split) + LSTM pointwise =====
        if (blk < 32) {
            const int d0 = blk * 16;
            f32x4 acc[4];
#pragma unroll
            for (int g = 0; g < 4; ++g) acc[g] = {0.f, 0.f, 0.f, 0.f};
            for (int k0 = 0; k0 < 1536; k0 += 32) {
                ((uint4*)Ash)[t] = *(const uint4*)(A_step + srow * ASTR + k0 + scsrc * 8);
                ((uint4*)Asl)[t] = *(const uint4*)(A_step + srow * ASTR + 1536 + k0 + scsrc * 8);
                int j = ((srow >> 4) << 9) + d0 + (srow & 15);
                ((uint4*)Bsh)[t] = *(const uint4*)(WT + (size_t)j * 3072 + k0 + scsrc * 8);
                ((uint4*)Bsl)[t] = *(const uint4*)(WT + (size_t)j * 3072 + 1536 + k0 + scsrc * 8);
                __syncthreads();
                short8 ah = Ash8[(wave * 16 + r16) * 4 + swz];
                short8 al = Asl8[(wave * 16 + r16) * 4 + swz];
#pragma unroll
                for (int g = 0; g < 4; ++g) {
                    short8 bh = Bsh8[(g * 16 + r16) * 4 + swz];
                    short8 bl = Bsl8[(g * 16 + r16) * 4 + swz];
                    acc[g] = __builtin_amdgcn_mfma_f32_16x16x32_bf16(ah, bh, acc[g], 0, 0, 0);
                    acc[g] = __builtin_amdgcn_mfma_f32_16x16x32_bf16(al, bh, acc[g], 0, 0, 0);
                    acc[g] = __builtin_amdgcn_mfma_f32_16x16x32_bf16(ah, bl, acc[g], 0, 0, 0);
                }
                __syncthreads();
            }
            int d = d0 + r16;
            float bi_ = b_ih[d] + b_hh[d];
            float bf_ = b_ih[d + 512] + b_hh[d + 512];
            float bg_ = b_ih[d + 1024] + b_hh[d + 1024];
            float bo_ = b_ih[d + 1536] + b_hh[d + 1536];
#pragma unroll
            for (int r = 0; r < 4; ++r) {
                int b = wave * 16 + kg * 4 + r;
                float gi = sigf(acc[0][r] + bi_);
                float gf = sigf(acc[1][r] + bf_);
                float gg = tanh_fast(acc[2][r] + bg_);
                float go = sigf(acc[3][r] + bo_);
                float cn = gf * cbuf[b * 512 + d] + gi * gg;
                float hn = go * tanh_fast(cn);
                cbuf[b * 512 + d] = cn;
                unsigned short hhi = f2bf(hn);
                unsigned short hlo = f2bf(hn - bf2f(hhi));
                A_step[b * ASTR + 1024 + d] = hhi;
                A_step[b * ASTR + 2560 + d] = hlo;
                hb[(size_t)((ts - 1) * 64 + b) * 512 + d] = hhi;
            }
        }
        gbar(bar);
    }
}

// ---------------- bf16 MFMA GEMM: C = A[M][512] * Bt[N][512]^T (+bias) ----------------
// MODE 0: enc_proj -> bf16 C[m][512], bias be_att (M=12544, N=512, exact tiles)
// MODE 1: vocab    -> scatter fp32 C[b][t+1][v], bias b_fc, guards (M=1920 pad, N=30080 pad)
template <int MODE>
__global__ __launch_bounds__(256) void gemm_mfma(const unsigned short* __restrict__ A,
                                                 const unsigned short* __restrict__ Bt,
                                                 const float* __restrict__ bias,
                                                 void* __restrict__ Cv) {
    constexpr int K = 512;
    __shared__ unsigned short As[128 * 32];
    __shared__ unsigned short Bs[128 * 32];
    const int t = threadIdx.x;
    const int m0 = blockIdx.y * 128;
    const int n0 = blockIdx.x * 128;
    const int lane = t & 63, wave = t >> 6;
    const int wm = wave >> 1, wn = wave & 1;
    const int r16 = lane & 15, kg = lane >> 4;
    const int swz = kg ^ ((r16 >> 1) & 3);

    f32x4 acc[4][4];
#pragma unroll
    for (int i = 0; i < 4; ++i)
#pragma unroll
        for (int j = 0; j < 4; ++j) acc[i][j] = {0.f, 0.f, 0.f, 0.f};

    const short8* As8 = (const short8*)As;
    const short8* Bs8 = (const short8*)Bs;

    for (int k0 = 0; k0 < K; k0 += 32) {
#pragma unroll
        for (int i = 0; i < 2; ++i) {
            int u = t + i * 256;
            int row = u >> 2, cs = u & 3;
            int csrc = cs ^ ((row >> 1) & 3);
            ((uint4*)As)[u] = *(const uint4*)(A + (size_t)(m0 + row) * K + k0 + csrc * 8);
            ((uint4*)Bs)[u] = *(const uint4*)(Bt + (size_t)(n0 + row) * K + k0 + csrc * 8);
        }
        __syncthreads();
        short8 af[4], bfr[4];
#pragma unroll
        for (int i = 0; i < 4; ++i) af[i] = As8[(wm * 64 + i * 16 + r16) * 4 + swz];
#pragma unroll
        for (int j = 0; j < 4; ++j) bfr[j] = Bs8[(wn * 64 + j * 16 + r16) * 4 + swz];
#pragma unroll
        for (int i = 0; i < 4; ++i)
#pragma unroll
            for (int j = 0; j < 4; ++j)
                acc[i][j] = __builtin_amdgcn_mfma_f32_16x16x32_bf16(af[i], bfr[j], acc[i][j], 0, 0, 0);
        __syncthreads();
    }

#pragma unroll
    for (int i = 0; i < 4; ++i) {
#pragma unroll
        for (int j = 0; j < 4; ++j) {
            int colg = n0 + wn * 64 + j * 16 + r16;
            float bv;
            if (MODE == 0) bv = bias[colg];
            else bv = (colg < VV) ? bias[colg] : 0.f;
#pragma unroll
            for (int r = 0; r < 4; ++r) {
                int rowg = m0 + wm * 64 + i * 16 + kg * 4 + r;
                float v = acc[i][j][r] + bv;
                if (MODE == 0) {
                    ((unsigned short*)Cv)[(size_t)rowg * 512 + colg] = f2bf(v);
                } else {
                    if (rowg < MROWS && colg < VV) {
                        int tt = rowg >> 6, bb2 = rowg & 63;
                        ((float*)Cv)[(size_t)bb2 * (TT * VV) + (size_t)(tt + 1) * VV + colg] = v;
                    }
                }
            }
        }
    }
}

extern "C" void kernel_launch(void* const* d_in, const int* in_sizes, int n_in,
                              void* d_out, int out_size, void* d_ws, size_t ws_size,
                              hipStream_t stream) {
    const float* feats   = (const float*)d_in[0];
    const float* pooled  = (const float*)d_in[1];
    const int*   caps    = (const int*)d_in[2];
    const float* We      = (const float*)d_in[3];
    const float* be      = (const float*)d_in[4];
    const float* Wd      = (const float*)d_in[5];
    const float* bd      = (const float*)d_in[6];
    const float* wfv     = (const float*)d_in[7];
    const float* emb     = (const float*)d_in[9];
    const float* W_ih    = (const float*)d_in[10];
    const float* W_hh    = (const float*)d_in[11];
    const float* b_ih    = (const float*)d_in[12];
    const float* b_hh    = (const float*)d_in[13];
    const float* W_inh   = (const float*)d_in[14];
    const float* b_inh   = (const float*)d_in[15];
    const float* W_inc   = (const float*)d_in[16];
    const float* b_inc   = (const float*)d_in[17];
    const float* Wfc     = (const float*)d_in[18];
    const float* bfc     = (const float*)d_in[19];
    const float* Wbeta   = (const float*)d_in[20];
    const float* bbeta   = (const float*)d_in[21];
    float* out = (float*)d_out;

    char* ws = (char*)d_ws;
    size_t off = 0;
    auto alloc = [&](size_t bytes) -> char* {
        char* p = ws + off;
        off += (bytes + 255) & ~(size_t)255;
        return p;
    };
    unsigned short* ep_bf = (unsigned short*)alloc((size_t)12544 * 512 * 2);  // enc_proj bf16
    unsigned short* fb    = (unsigned short*)alloc((size_t)12544 * 512 * 2);  // feats bf16
    unsigned short* WeT   = (unsigned short*)alloc((size_t)512 * 512 * 2);    // We^T
    unsigned short* WfcT  = (unsigned short*)alloc((size_t)VPAD * 512 * 2);   // Wfc^T (padded)
    unsigned short* WdbT  = (unsigned short*)alloc((size_t)1024 * 1024 * 2);  // [Wd|Wb]^T split hi/lo
    unsigned short* WT    = (unsigned short*)alloc((size_t)2048 * 3072 * 2);  // [W_ih;W_hh]^T split hi/lo
    unsigned short* hb    = (unsigned short*)alloc((size_t)MPAD * 512 * 2);   // h_all bf16
    unsigned short* A_step= (unsigned short*)alloc((size_t)64 * ASTR * 2);    // [x|h] split bf16
    float*          cbuf  = (float*)alloc((size_t)64 * 512 * 4);
    float*          decp  = (float*)alloc((size_t)64 * 512 * 4);
    float*          betap = (float*)alloc((size_t)64 * 512 * 4);
    int*            bar   = (int*)alloc(256);
    (void)ws_size; (void)in_sizes; (void)n_in; (void)out_size;

    // precompute
    k_cast<<<2048, 256, 0, stream>>>(feats, fb, 12544 * 512);
    k_transpose_cast<<<dim3(16, 16), 256, 0, stream>>>(We, WeT, 512, 512, 512, 512, 0);
    k_transpose_cast<<<dim3(940, 16), 256, 0, stream>>>(Wfc, WfcT, 512, VV, VPAD, 512, 0);
    k_transpose_cast_split<<<dim3(16, 16), 256, 0, stream>>>(Wd, WdbT, 512, 512, 1024, 0, 512);
    k_transpose_cast_split<<<dim3(16, 16), 256, 0, stream>>>(Wbeta, WdbT + (size_t)512 * 1024, 512, 512, 1024, 0, 512);
    k_transpose_cast_split<<<dim3(64, 32), 256, 0, stream>>>(W_ih, WT, 1024, 2048, 3072, 0, 1536);
    k_transpose_cast_split<<<dim3(64, 16), 256, 0, stream>>>(W_hh, WT, 512, 2048, 3072, 1024, 2560);
    k_init<<<128, 256, 0, stream>>>(pooled, W_inh, b_inh, W_inc, b_inc, A_step, cbuf, bar);
    gemm_mfma<0><<<dim3(4, 98), 256, 0, stream>>>(fb, WeT, be, ep_bf);
    k_zero0<<<7500, 256, 0, stream>>>(out);

    // persistent recurrence (29 steps, 3 grid barriers per step)
    k_recur<<<NBLK, 256, 0, stream>>>(ep_bf, fb, WdbT, WT, bd, bbeta, wfv, caps, emb,
                                      b_ih, b_hh, A_step, cbuf, decp, betap, hb, bar);

    // batched vocab projection for all 29 steps
    gemm_mfma<1><<<dim3(235, 15), 256, 0, stream>>>(hb, WfcT, bfc, out);
}

// Round 3
// 3639.322 us; speedup vs baseline: 1.1263x; 1.1263x over previous
//
#include <hip/hip_runtime.h>
#include <hip/hip_bf16.h>

// B=64, P=196, T=30, E=D=A=ENC=512, V=30000
#define BB 64
#define PP 196
#define TT 30
#define DD 512
#define VV 30000
#define VPAD 30080           // 235*128
#define MROWS 1856           // 29*64
#define MPAD 1920            // 15*128
#define NBLK 64              // persistent kernel grid
// A_step row: [x_hi(1024) | h_hi0(512) | h_hi1(512) | x_lo(1024) | h_lo0(512) | h_lo1(512)]
// h double-buffered: step ts reads slot (ts&1), Phase C writes slot (ts&1)^1.
#define ASTR 4096

typedef __attribute__((ext_vector_type(8))) short short8;
typedef __attribute__((ext_vector_type(4))) float f32x4;

__device__ __forceinline__ unsigned short f2bf(float f) {
    unsigned int u = __float_as_uint(f);
    unsigned int r = u + 0x7FFFu + ((u >> 16) & 1u);
    return (unsigned short)(r >> 16);
}
__device__ __forceinline__ float bf2f(unsigned short u) {
    return __uint_as_float(((unsigned int)u) << 16);
}
__device__ __forceinline__ float sigf(float x) { return 1.f / (1.f + __expf(-x)); }
__device__ __forceinline__ float tanh_fast(float x) { return 1.f - 2.f / (1.f + __expf(2.f * x)); }

// ---------------- cast fp32 -> bf16 ----------------
__global__ __launch_bounds__(256) void k_cast(const float* __restrict__ in,
                                              unsigned short* __restrict__ out, int n) {
    int i = blockIdx.x * 256 + threadIdx.x;
    int stride = gridDim.x * 256;
    for (; i < n; i += stride) out[i] = f2bf(in[i]);
}

// ------- transpose fp32 [R][C] -> bf16 out[outr][ostride] at +ooff, zero-fill C..Cpad -------
__global__ __launch_bounds__(256) void k_transpose_cast(const float* __restrict__ in,
                                                        unsigned short* __restrict__ out,
                                                        int R, int C, int Cpad, int ostride, int ooff) {
    __shared__ float tile[32][33];
    int tx = threadIdx.x & 31, ty = threadIdx.x >> 5;  // 32 x 8
    int c0 = blockIdx.x * 32, r0 = blockIdx.y * 32;
#pragma unroll
    for (int i = 0; i < 4; ++i) {
        int r = r0 + ty + i * 8, c = c0 + tx;
        tile[ty + i * 8][tx] = (c < C) ? in[(size_t)r * C + c] : 0.f;
    }
    __syncthreads();
#pragma unroll
    for (int i = 0; i < 4; ++i) {
        int outr = c0 + ty + i * 8, outc = r0 + tx;
        if (outr < Cpad) out[(size_t)outr * ostride + ooff + outc] = f2bf(tile[tx][ty + i * 8]);
    }
}

// ------- transpose fp32 [R][C] -> split bf16 (hi at ooff, lo at looff), exact tiles -------
__global__ __launch_bounds__(256) void k_transpose_cast_split(const float* __restrict__ in,
                                                              unsigned short* __restrict__ out,
                                                              int R, int C, int ostride,
                                                              int ooff, int looff) {
    __shared__ float tile[32][33];
    int tx = threadIdx.x & 31, ty = threadIdx.x >> 5;  // 32 x 8
    int c0 = blockIdx.x * 32, r0 = blockIdx.y * 32;
#pragma unroll
    for (int i = 0; i < 4; ++i) {
        int r = r0 + ty + i * 8, c = c0 + tx;
        tile[ty + i * 8][tx] = in[(size_t)r * C + c];
    }
    __syncthreads();
#pragma unroll
    for (int i = 0; i < 4; ++i) {
        int outr = c0 + ty + i * 8, outc = r0 + tx;
        float v = tile[tx][ty + i * 8];
        unsigned short hi = f2bf(v);
        unsigned short lo = f2bf(v - bf2f(hi));
        out[(size_t)outr * ostride + ooff + outc] = hi;
        out[(size_t)outr * ostride + looff + outc] = lo;
    }
}

// ---------------- zero out[:, 0, :] ----------------
__global__ __launch_bounds__(256) void k_zero0(float* __restrict__ out) {
    int i = blockIdx.x * 256 + threadIdx.x;  // 64*30000
    int b = i / VV, v = i - b * VV;
    out[(size_t)b * (TT * VV) + v] = 0.f;
}

// ---------------- init h0 (split bf16, BOTH h slots), c0 (fp32), zero barrier ----------------
__global__ __launch_bounds__(256) void k_init(const float* __restrict__ pooled,
                                              const float* __restrict__ Wh, const float* __restrict__ bh,
                                              const float* __restrict__ Wc, const float* __restrict__ bc,
                                              unsigned short* __restrict__ A_step,
                                              float* __restrict__ cbuf, int* __restrict__ bar) {
    int b = blockIdx.x >> 1, which = blockIdx.x & 1, t = threadIdx.x;
    if (blockIdx.x == 0) {
        for (int i = t; i < NBLK * 32 + 32; i += 256) bar[i] = 0;
    }
    const float* W = which ? Wc : Wh;
    const float* bias = which ? bc : bh;
    const float* pr = pooled + b * DD;
    float a0 = 0.f, a1 = 0.f;
#pragma unroll 4
    for (int k = 0; k < DD; ++k) {
        float pv = pr[k];
        a0 += pv * W[k * DD + t];
        a1 += pv * W[k * DD + t + 256];
    }
    float v0 = tanh_fast(a0 + bias[t]);
    float v1 = tanh_fast(a1 + bias[t + 256]);
    if (which == 0) {
        unsigned short hi0 = f2bf(v0), lo0 = f2bf(v0 - bf2f(hi0));
        unsigned short hi1 = f2bf(v1), lo1 = f2bf(v1 - bf2f(hi1));
        unsigned short* xr = A_step + b * ASTR;
        // both h slots
        xr[1024 + t] = hi0;        xr[1536 + t] = hi0;
        xr[3072 + t] = lo0;        xr[3584 + t] = lo0;
        xr[1024 + t + 256] = hi1;  xr[1536 + t + 256] = hi1;
        xr[3072 + t + 256] = lo1;  xr[3584 + t + 256] = lo1;
    } else {
        cbuf[b * DD + t] = v0;
        cbuf[b * DD + t + 256] = v1;
    }
}

// -------- device-scope grid barrier: parallel per-block flags + single publisher --------
// bar layout: flags at bar[i*32] (one line per block), gen at bar[NBLK*32].
// Block i release-stores generation g to its own flag; block 0 polls all flags in
// parallel, then release-publishes gen=g. Monotonic g => no reset, no contended RMW.
__device__ __forceinline__ void gbar(int* bar, int g) {
    __syncthreads();
    if (blockIdx.x == 0) {
        int t = threadIdx.x;
        if (t >= 1 && t < NBLK) {
            while (__hip_atomic_load(&bar[t * 32], __ATOMIC_ACQUIRE, __HIP_MEMORY_SCOPE_AGENT) < g)
                __builtin_amdgcn_s_sleep(1);
        }
        __syncthreads();
        if (t == 0)
            __hip_atomic_store(&bar[NBLK * 32], g, __ATOMIC_RELEASE, __HIP_MEMORY_SCOPE_AGENT);
    } else {
        if (threadIdx.x == 0) {
            __hip_atomic_store(&bar[blockIdx.x * 32], g, __ATOMIC_RELEASE, __HIP_MEMORY_SCOPE_AGENT);
            while (__hip_atomic_load(&bar[NBLK * 32], __ATOMIC_ACQUIRE, __HIP_MEMORY_SCOPE_AGENT) < g)
                __builtin_amdgcn_s_sleep(1);
        }
        __syncthreads();
    }
}

// ---------------- persistent recurrence kernel: 29 steps, 3 grid syncs/step ----------------
// Recurrent GEMMs use double-bf16 (hi/lo) 3-product MFMA: a*b ~= ah*bh + al*bh + ah*bl
__global__ __launch_bounds__(256, 1) void k_recur(
    const unsigned short* __restrict__ ep,    // [64*196][512] bf16 enc_proj
    const unsigned short* __restrict__ fb,    // [64*196][512] bf16 feats
    const unsigned short* __restrict__ WdbT,  // [1024][1024]  rows: [Wd|Wbeta] cols, [hi(512)|lo(512)]
    const unsigned short* __restrict__ WT,    // [2048][3072]  rows j: [Wih;Whh]^T, [hi(1536)|lo(1536)]
    const float* __restrict__ bd,
    const float* __restrict__ bbeta,
    const float* __restrict__ wfv,
    const int* __restrict__ caps,
    const float* __restrict__ emb,
    const float* __restrict__ b_ih,
    const float* __restrict__ b_hh,
    unsigned short* __restrict__ A_step,      // [64][4096] bf16 (see ASTR layout)
    float* __restrict__ cbuf,                 // [64][512] fp32
    float* __restrict__ decp,                 // [64][512] fp32
    float* __restrict__ betap,                // [64][512] fp32
    unsigned short* __restrict__ hb,          // [29*64][512] bf16
    int* __restrict__ bar) {

    const int blk = blockIdx.x, t = threadIdx.x;
    const int lane = t & 63, wave = t >> 6;
    const int r16 = lane & 15, kg = lane >> 4;
    const int swz = kg ^ ((r16 >> 1) & 3);

    __shared__ unsigned short Ash[64 * 32];
    __shared__ unsigned short Asl[64 * 32];
    __shared__ unsigned short Bsh[64 * 32];
    __shared__ unsigned short Bsl[64 * 32];
    __shared__ float dec_s[DD];
    __shared__ float wf_s[DD];
    __shared__ float sc_s[256];
    __shared__ float red_s[16];
    __shared__ float ctx_s[4][512];

    const short8* Ash8 = (const short8*)Ash;
    const short8* Asl8 = (const short8*)Asl;
    const short8* Bsh8 = (const short8*)Bsh;
    const short8* Bsl8 = (const short8*)Bsl;
    const int srow = t >> 2, scs = t & 3;
    const int scsrc = scs ^ ((srow >> 1) & 3);

    int gph = 0;

    for (int ts = 1; ts < TT; ++ts) {
        const int par = ts & 1;          // h slot read this step
        const int hh = 1024 + par * 512; // h_hi[par] offset
        const int hl = 3072 + par * 512; // h_lo[par] offset

        // ===== Phase A (blocks 0..31): [dec|beta] = h @ [Wd|Wb]  (M=64,N=32/blk,K=512) =====
        if (blk < 32) {
            const int n0 = blk * 32;
            f32x4 acc[2];
#pragma unroll
            for (int j = 0; j < 2; ++j) acc[j] = {0.f, 0.f, 0.f, 0.f};
            for (int k0 = 0; k0 < 512; k0 += 32) {
                ((uint4*)Ash)[t] = *(const uint4*)(A_step + srow * ASTR + hh + k0 + scsrc * 8);
                ((uint4*)Asl)[t] = *(const uint4*)(A_step + srow * ASTR + hl + k0 + scsrc * 8);
                if (t < 128) {
                    ((uint4*)Bsh)[t] = *(const uint4*)(WdbT + (size_t)(n0 + srow) * 1024 + k0 + scsrc * 8);
                    ((uint4*)Bsl)[t] = *(const uint4*)(WdbT + (size_t)(n0 + srow) * 1024 + 512 + k0 + scsrc * 8);
                }
                __syncthreads();
                short8 ah = Ash8[(wave * 16 + r16) * 4 + swz];
                short8 al = Asl8[(wave * 16 + r16) * 4 + swz];
#pragma unroll
                for (int j = 0; j < 2; ++j) {
                    short8 bh = Bsh8[(j * 16 + r16) * 4 + swz];
                    short8 bl = Bsl8[(j * 16 + r16) * 4 + swz];
                    acc[j] = __builtin_amdgcn_mfma_f32_16x16x32_bf16(ah, bh, acc[j], 0, 0, 0);
                    acc[j] = __builtin_amdgcn_mfma_f32_16x16x32_bf16(al, bh, acc[j], 0, 0, 0);
                    acc[j] = __builtin_amdgcn_mfma_f32_16x16x32_bf16(ah, bl, acc[j], 0, 0, 0);
                }
                __syncthreads();
            }
#pragma unroll
            for (int j = 0; j < 2; ++j) {
                int col = n0 + j * 16 + r16;
#pragma unroll
                for (int r = 0; r < 4; ++r) {
                    int b = wave * 16 + kg * 4 + r;
                    float v = acc[j][r];
                    if (col < 512) decp[b * 512 + col] = v + bd[col];
                    else betap[b * 512 + (col - 512)] = sigf(v + bbeta[col - 512]);
                }
            }
        }
        gbar(bar, ++gph);

        // ===== Phase B (all 64 blocks, one per b): attention + x assembly =====
        {
            const int b = blk;
            dec_s[t] = decp[b * 512 + t];
            dec_s[t + 256] = decp[b * 512 + t + 256];
            wf_s[t] = wfv[t];
            wf_s[t + 256] = wfv[t + 256];
            __syncthreads();
            const unsigned short* epb = ep + (size_t)(b * PP) * 512;
            for (int p = wave; p < PP; p += 4) {
                uint4 pk = *(const uint4*)(epb + p * 512 + lane * 8);
                const unsigned short* pu = (const unsigned short*)&pk;
                float s = 0.f;
#pragma unroll
                for (int j = 0; j < 8; ++j) {
                    int a = lane * 8 + j;
                    float v = bf2f(pu[j]) + dec_s[a];
                    s += tanh_fast(v) * wf_s[a];
                }
#pragma unroll
                for (int off = 32; off; off >>= 1) s += __shfl_xor(s, off);
                if (lane == 0) sc_s[p] = s;
            }
            __syncthreads();
            float sv = (t < PP) ? sc_s[t] : -1e30f;
            float m = sv;
#pragma unroll
            for (int off = 32; off; off >>= 1) m = fmaxf(m, __shfl_xor(m, off));
            if (lane == 0) red_s[wave] = m;
            __syncthreads();
            float mx = fmaxf(fmaxf(red_s[0], red_s[1]), fmaxf(red_s[2], red_s[3]));
            float e = (t < PP) ? __expf(sv - mx) : 0.f;
            float ssum = e;
#pragma unroll
            for (int off = 32; off; off >>= 1) ssum += __shfl_xor(ssum, off);
            if (lane == 0) red_s[8 + wave] = ssum;
            __syncthreads();
            float inv = 1.f / (red_s[8] + red_s[9] + red_s[10] + red_s[11]);
            if (t < PP) sc_s[t] = e * inv;
            __syncthreads();
            // ctx GEMV vectorized: lane owns 8 contiguous dims, waves split P
            const unsigned short* fbb = fb + (size_t)(b * PP) * 512;
            const int d8 = lane * 8;
            float c[8];
#pragma unroll
            for (int j = 0; j < 8; ++j) c[j] = 0.f;
#pragma unroll 4
            for (int p = wave; p < PP; p += 4) {
                float a = sc_s[p];
                uint4 pk = *(const uint4*)(fbb + p * 512 + d8);
                const unsigned short* pu = (const unsigned short*)&pk;
#pragma unroll
                for (int j = 0; j < 8; ++j) c[j] += a * bf2f(pu[j]);
            }
#pragma unroll
            for (int j = 0; j < 8; ++j) ctx_s[wave][d8 + j] = c[j];
            __syncthreads();
            float ctx0 = ctx_s[0][t] + ctx_s[1][t] + ctx_s[2][t] + ctx_s[3][t];
            float ctx1 = ctx_s[0][t + 256] + ctx_s[1][t + 256] + ctx_s[2][t + 256] + ctx_s[3][t + 256];
            float g0 = betap[b * 512 + t], g1 = betap[b * 512 + t + 256];
            int tok = caps[b * TT + (ts - 1)];
            const float* er = emb + (size_t)tok * 512;
            unsigned short* xr = A_step + b * ASTR;
            {
                float v;
                unsigned short hi;
                v = er[t];             hi = f2bf(v); xr[t] = hi;           xr[2048 + t] = f2bf(v - bf2f(hi));
                v = er[t + 256];       hi = f2bf(v); xr[t + 256] = hi;     xr[2304 + t] = f2bf(v - bf2f(hi));
                v = g0 * ctx0;         hi = f2bf(v); xr[512 + t] = hi;     xr[2560 + t] = f2bf(v - bf2f(hi));
                v = g1 * ctx1;         hi = f2bf(v); xr[768 + t] = hi;     xr[2816 + t] = f2bf(v - bf2f(hi));
            }
        }
        gbar(bar, ++gph);

        // ===== Phase C (blocks 0..31): gates GEMM (M=64,N=16x4gates,K=1536 split) + LSTM pointwise =====
        // reads h slot par, writes h slot par^1 (no same-phase read/write overlap)
        if (blk < 32) {
            const int d0 = blk * 16;
            f32x4 acc[4];
#pragma unroll
            for (int g = 0; g < 4; ++g) acc[g] = {0.f, 0.f, 0.f, 0.f};
            for (int k0 = 0; k0 < 1536; k0 += 32) {
                const int src = (k0 < 1024) ? k0 : (k0 + par * 512);
                ((uint4*)Ash)[t] = *(const uint4*)(A_step + srow * ASTR + src + scsrc * 8);
                ((uint4*)Asl)[t] = *(const uint4*)(A_step + srow * ASTR + 2048 + src + scsrc * 8);
                int j = ((srow >> 4) << 9) + d0 + (srow & 15);
                ((uint4*)Bsh)[t] = *(const uint4*)(WT + (size_t)j * 3072 + k0 + scsrc * 8);
                ((uint4*)Bsl)[t] = *(const uint4*)(WT + (size_t)j * 3072 + 1536 + k0 + scsrc * 8);
                __syncthreads();
                short8 ah = Ash8[(wave * 16 + r16) * 4 + swz];
                short8 al = Asl8[(wave * 16 + r16) * 4 + swz];
#pragma unroll
                for (int g = 0; g < 4; ++g) {
                    short8 bh = Bsh8[(g * 16 + r16) * 4 + swz];
                    short8 bl = Bsl8[(g * 16 + r16) * 4 + swz];
                    acc[g] = __builtin_amdgcn_mfma_f32_16x16x32_bf16(ah, bh, acc[g], 0, 0, 0);
                    acc[g] = __builtin_amdgcn_mfma_f32_16x16x32_bf16(al, bh, acc[g], 0, 0, 0);
                    acc[g] = __builtin_amdgcn_mfma_f32_16x16x32_bf16(ah, bl, acc[g], 0, 0, 0);
                }
                __syncthreads();
            }
            const int whh = 1024 + (par ^ 1) * 512;  // h_hi write slot
            const int whl = 3072 + (par ^ 1) * 512;  // h_lo write slot
            int d = d0 + r16;
            float bi_ = b_ih[d] + b_hh[d];
            float bf_ = b_ih[d + 512] + b_hh[d + 512];
            float bg_ = b_ih[d + 1024] + b_hh[d + 1024];
            float bo_ = b_ih[d + 1536] + b_hh[d + 1536];
#pragma unroll
            for (int r = 0; r < 4; ++r) {
                int b = wave * 16 + kg * 4 + r;
                float gi = sigf(acc[0][r] + bi_);
                float gf = sigf(acc[1][r] + bf_);
                float gg = tanh_fast(acc[2][r] + bg_);
                float go = sigf(acc[3][r] + bo_);
                float cn = gf * cbuf[b * 512 + d] + gi * gg;
                float hn = go * tanh_fast(cn);
                cbuf[b * 512 + d] = cn;
                unsigned short hhi = f2bf(hn);
                unsigned short hlo = f2bf(hn - bf2f(hhi));
                A_step[b * ASTR + whh + d] = hhi;
                A_step[b * ASTR + whl + d] = hlo;
                hb[(size_t)((ts - 1) * 64 + b) * 512 + d] = hhi;
            }
        }
        gbar(bar, ++gph);
    }
}

// ---------------- bf16 MFMA GEMM: C = A[M][512] * Bt[N][512]^T (+bias) ----------------
// MODE 0: enc_proj -> bf16 C[m][512], bias be_att (M=12544, N=512, exact tiles)
// MODE 1: vocab    -> scatter fp32 C[b][t+1][v], bias b_fc, guards (M=1920 pad, N=30080 pad)
template <int MODE>
__global__ __launch_bounds__(256) void gemm_mfma(const unsigned short* __restrict__ A,
                                                 const unsigned short* __restrict__ Bt,
                                                 const float* __restrict__ bias,
                                                 void* __restrict__ Cv) {
    constexpr int K = 512;
    __shared__ unsigned short As[128 * 32];
    __shared__ unsigned short Bs[128 * 32];
    const int t = threadIdx.x;
    const int m0 = blockIdx.y * 128;
    const int n0 = blockIdx.x * 128;
    const int lane = t & 63, wave = t >> 6;
    const int wm = wave >> 1, wn = wave & 1;
    const int r16 = lane & 15, kg = lane >> 4;
    const int swz = kg ^ ((r16 >> 1) & 3);

    f32x4 acc[4][4];
#pragma unroll
    for (int i = 0; i < 4; ++i)
#pragma unroll
        for (int j = 0; j < 4; ++j) acc[i][j] = {0.f, 0.f, 0.f, 0.f};

    const short8* As8 = (const short8*)As;
    const short8* Bs8 = (const short8*)Bs;

    for (int k0 = 0; k0 < K; k0 += 32) {
#pragma unroll
        for (int i = 0; i < 2; ++i) {
            int u = t + i * 256;
            int row = u >> 2, cs = u & 3;
            int csrc = cs ^ ((row >> 1) & 3);
            ((uint4*)As)[u] = *(const uint4*)(A + (size_t)(m0 + row) * K + k0 + csrc * 8);
            ((uint4*)Bs)[u] = *(const uint4*)(Bt + (size_t)(n0 + row) * K + k0 + csrc * 8);
        }
        __syncthreads();
        short8 af[4], bfr[4];
#pragma unroll
        for (int i = 0; i < 4; ++i) af[i] = As8[(wm * 64 + i * 16 + r16) * 4 + swz];
#pragma unroll
        for (int j = 0; j < 4; ++j) bfr[j] = Bs8[(wn * 64 + j * 16 + r16) * 4 + swz];
#pragma unroll
        for (int i = 0; i < 4; ++i)
#pragma unroll
            for (int j = 0; j < 4; ++j)
                acc[i][j] = __builtin_amdgcn_mfma_f32_16x16x32_bf16(af[i], bfr[j], acc[i][j], 0, 0, 0);
        __syncthreads();
    }

#pragma unroll
    for (int i = 0; i < 4; ++i) {
#pragma unroll
        for (int j = 0; j < 4; ++j) {
            int colg = n0 + wn * 64 + j * 16 + r16;
            float bv;
            if (MODE == 0) bv = bias[colg];
            else bv = (colg < VV) ? bias[colg] : 0.f;
#pragma unroll
            for (int r = 0; r < 4; ++r) {
                int rowg = m0 + wm * 64 + i * 16 + kg * 4 + r;
                float v = acc[i][j][r] + bv;
                if (MODE == 0) {
                    ((unsigned short*)Cv)[(size_t)rowg * 512 + colg] = f2bf(v);
                } else {
                    if (rowg < MROWS && colg < VV) {
                        int tt = rowg >> 6, bb2 = rowg & 63;
                        ((float*)Cv)[(size_t)bb2 * (TT * VV) + (size_t)(tt + 1) * VV + colg] = v;
                    }
                }
            }
        }
    }
}

extern "C" void kernel_launch(void* const* d_in, const int* in_sizes, int n_in,
                              void* d_out, int out_size, void* d_ws, size_t ws_size,
                              hipStream_t stream) {
    const float* feats   = (const float*)d_in[0];
    const float* pooled  = (const float*)d_in[1];
    const int*   caps    = (const int*)d_in[2];
    const float* We      = (const float*)d_in[3];
    const float* be      = (const float*)d_in[4];
    const float* Wd      = (const float*)d_in[5];
    const float* bd      = (const float*)d_in[6];
    const float* wfv     = (const float*)d_in[7];
    const float* emb     = (const float*)d_in[9];
    const float* W_ih    = (const float*)d_in[10];
    const float* W_hh    = (const float*)d_in[11];
    const float* b_ih    = (const float*)d_in[12];
    const float* b_hh    = (const float*)d_in[13];
    const float* W_inh   = (const float*)d_in[14];
    const float* b_inh   = (const float*)d_in[15];
    const float* W_inc   = (const float*)d_in[16];
    const float* b_inc   = (const float*)d_in[17];
    const float* Wfc     = (const float*)d_in[18];
    const float* bfc     = (const float*)d_in[19];
    const float* Wbeta   = (const float*)d_in[20];
    const float* bbeta   = (const float*)d_in[21];
    float* out = (float*)d_out;

    char* ws = (char*)d_ws;
    size_t off = 0;
    auto alloc = [&](size_t bytes) -> char* {
        char* p = ws + off;
        off += (bytes + 255) & ~(size_t)255;
        return p;
    };
    unsigned short* ep_bf = (unsigned short*)alloc((size_t)12544 * 512 * 2);  // enc_proj bf16
    unsigned short* fb    = (unsigned short*)alloc((size_t)12544 * 512 * 2);  // feats bf16
    unsigned short* WeT   = (unsigned short*)alloc((size_t)512 * 512 * 2);    // We^T
    unsigned short* WfcT  = (unsigned short*)alloc((size_t)VPAD * 512 * 2);   // Wfc^T (padded)
    unsigned short* WdbT  = (unsigned short*)alloc((size_t)1024 * 1024 * 2);  // [Wd|Wb]^T split hi/lo
    unsigned short* WT    = (unsigned short*)alloc((size_t)2048 * 3072 * 2);  // [W_ih;W_hh]^T split hi/lo
    unsigned short* hb    = (unsigned short*)alloc((size_t)MPAD * 512 * 2);   // h_all bf16
    unsigned short* A_step= (unsigned short*)alloc((size_t)64 * ASTR * 2);    // [x|h,h] split bf16
    float*          cbuf  = (float*)alloc((size_t)64 * 512 * 4);
    float*          decp  = (float*)alloc((size_t)64 * 512 * 4);
    float*          betap = (float*)alloc((size_t)64 * 512 * 4);
    int*            bar   = (int*)alloc((size_t)(NBLK * 32 + 32) * 4);
    (void)ws_size; (void)in_sizes; (void)n_in; (void)out_size;

    // precompute
    k_cast<<<2048, 256, 0, stream>>>(feats, fb, 12544 * 512);
    k_transpose_cast<<<dim3(16, 16), 256, 0, stream>>>(We, WeT, 512, 512, 512, 512, 0);
    k_transpose_cast<<<dim3(940, 16), 256, 0, stream>>>(Wfc, WfcT, 512, VV, VPAD, 512, 0);
    k_transpose_cast_split<<<dim3(16, 16), 256, 0, stream>>>(Wd, WdbT, 512, 512, 1024, 0, 512);
    k_transpose_cast_split<<<dim3(16, 16), 256, 0, stream>>>(Wbeta, WdbT + (size_t)512 * 1024, 512, 512, 1024, 0, 512);
    k_transpose_cast_split<<<dim3(64, 32), 256, 0, stream>>>(W_ih, WT, 1024, 2048, 3072, 0, 1536);
    k_transpose_cast_split<<<dim3(64, 16), 256, 0, stream>>>(W_hh, WT, 512, 2048, 3072, 1024, 2560);
    k_init<<<128, 256, 0, stream>>>(pooled, W_inh, b_inh, W_inc, b_inc, A_step, cbuf, bar);
    gemm_mfma<0><<<dim3(4, 98), 256, 0, stream>>>(fb, WeT, be, ep_bf);
    k_zero0<<<7500, 256, 0, stream>>>(out);

    // persistent recurrence (29 steps, 3 grid barriers per step)
    k_recur<<<NBLK, 256, 0, stream>>>(ep_bf, fb, WdbT, WT, bd, bbeta, wfv, caps, emb,
                                      b_ih, b_hh, A_step, cbuf, decp, betap, hb, bar);

    // batched vocab projection for all 29 steps
    gemm_mfma<1><<<dim3(235, 15), 256, 0, stream>>>(hb, WfcT, bfc, out);
}